// Round 1
// baseline (588.496 us; speedup 1.0000x reference)
//
#include <hip/hip_runtime.h>
#include <hip/hip_bf16.h>

// ---------------------------------------------------------------------------
// BlipAttention: x(32,1024,768) -> qkv -> attention -> scramble -> proj
// R7: 256x256 deep-pipelined GEMM (8 waves, BK=64, 4 sub-phases/K-tile):
//     T2 chunk-XOR swizzle (stored[r][c]=orig[r][c^(r&7)], pre-swizzled
//     global src for global_load_lds), T3-style fine interleave with raw
//     s_barrier pairs per phase, prefetch issued phases 0/1 (>=3 phases in
//     flight at the boundary __syncthreads), T5 setprio around MFMA,
//     16x16x32 bf16 MFMA, acc[8][4] f32x4 = 128 VGPR.
// ---------------------------------------------------------------------------

#define BM 256
#define BN 256
#define BKK 64

typedef __attribute__((ext_vector_type(8))) short bf16x8;
typedef __attribute__((ext_vector_type(4))) float f32x4;

__device__ __forceinline__ unsigned short f2b(float f) {
  unsigned int u = __float_as_uint(f);
  u = u + 0x7fffu + ((u >> 16) & 1u);
  return (unsigned short)(u >> 16);
}

__device__ __forceinline__ void g2l16(const void* g, void* l) {
  __builtin_amdgcn_global_load_lds(
      (const __attribute__((address_space(1))) unsigned int*)g,
      (__attribute__((address_space(3))) unsigned int*)l, 16, 0, 0);
}

// NT GEMM: C[m][n] = sum_k A[m][k] * B[n][k]; A,B bf16 row-major (K contig).
// EPI 1: QKV split: bias add, write Q/K/V bf16 (seg = col0/768)
// EPI 2: fp32 out + bias
// EPI 3: E = exp(v*scale) bf16 out + atomic row-sum accumulation into Z
// EPI 4: bf16 out = v * (1/Z[col])
template <int EPI, int SWAP>
__global__ __launch_bounds__(512, 2) void gemm_nt8(
    const unsigned short* __restrict__ A, const unsigned short* __restrict__ B,
    unsigned short* __restrict__ Cb, unsigned short* __restrict__ Ck,
    unsigned short* __restrict__ Cv, float* __restrict__ Cf,
    const float* __restrict__ bias, float* __restrict__ Z, int K, int lda,
    int ldb, int ldc, long bsA, long bsB, long bsC, float scale) {
  __shared__ unsigned short As[2][BM][BKK];  // 64 KB
  __shared__ unsigned short Bs[2][BN][BKK];  // 64 KB

  const int bxn = SWAP ? blockIdx.y : blockIdx.x;  // N-tile
  const int bym = SWAP ? blockIdx.x : blockIdx.y;  // M-tile
  const int bz = blockIdx.z;
  const unsigned short* Ag = A + (long)bz * bsA + (long)(bym * BM) * lda;
  const unsigned short* Bg = B + (long)bz * bsB + (long)(bxn * BN) * ldb;

  const int tid = threadIdx.x;
  const int wave = tid >> 6;
  const int lane = tid & 63;
  const int l15 = lane & 15;
  const int lk = lane >> 4;           // 0..3
  const int wm = (wave >> 2) << 7;    // wave A-row offset (0/128)
  const int wn = (wave & 3) << 6;     // wave B-row offset (0/64/128/192)

  // staging map: issue covers 8 rows x 8 chunks; lane -> row sr, chunk sc^sr
  const int sr = lane >> 3;
  const int sc = (lane & 7) ^ sr;  // pre-swizzled global 16B chunk

  f32x4 acc[8][4];
#pragma unroll
  for (int m = 0; m < 8; ++m)
#pragma unroll
    for (int n = 0; n < 4; ++n)
#pragma unroll
      for (int p = 0; p < 4; ++p) acc[m][n][p] = 0.f;

  auto stA = [&](int d, int h, int k0) {
#pragma unroll
    for (int i = 0; i < 2; ++i) {
      const int rb = (h << 7) + (wave << 4) + (i << 3);
      g2l16(Ag + (long)(rb + sr) * lda + k0 + (sc << 3), &As[d][rb][0]);
    }
  };
  auto stB = [&](int d, int h, int k0) {
#pragma unroll
    for (int i = 0; i < 2; ++i) {
      const int rb = (h << 7) + (wave << 4) + (i << 3);
      g2l16(Bg + (long)(rb + sr) * ldb + k0 + (sc << 3), &Bs[d][rb][0]);
    }
  };
  // frag reads: row r, want k-chunk c=(ks*4+lk) -> stored chunk c^(r&7)
  auto ldA = [&](int d, int m, int ks) {
    return *(const bf16x8*)&As[d][wm + (m << 4) + l15]
                              [((((ks << 2) | lk) ^ (l15 & 7)) << 3)];
  };
  auto ldB = [&](int d, int n, int ks) {
    return *(const bf16x8*)&Bs[d][wn + (n << 4) + l15]
                              [((((ks << 2) | lk) ^ (l15 & 7)) << 3)];
  };

  const int NT = K / BKK;
  // prologue: stage tile0 -> buf0, tile1 -> buf1; counted wait for tile0 only
  stA(0, 0, 0); stA(0, 1, 0); stB(0, 0, 0); stB(0, 1, 0);
  stA(1, 0, BKK); stA(1, 1, BKK); stB(1, 0, BKK); stB(1, 1, BKK);
  asm volatile("s_waitcnt vmcnt(8)" ::: "memory");
  __builtin_amdgcn_sched_barrier(0);
  __builtin_amdgcn_s_barrier();

  int cur = 0;
  for (int t = 0; t < NT; ++t) {
    const int nxt = cur ^ 1;
    const bool st = (t >= 1) && (t + 1 < NT);
    const int k1 = (t + 1) * BKK;

    // ---- phase 0: read A m0-3 + B n0-1, stage A halves of tile t+1
    bf16x8 aL[4][2], bA[2][2];
#pragma unroll
    for (int m = 0; m < 4; ++m)
#pragma unroll
      for (int ks = 0; ks < 2; ++ks) aL[m][ks] = ldA(cur, m, ks);
#pragma unroll
    for (int n = 0; n < 2; ++n)
#pragma unroll
      for (int ks = 0; ks < 2; ++ks) bA[n][ks] = ldB(cur, n, ks);
    if (st) { stA(nxt, 0, k1); stA(nxt, 1, k1); }
    __builtin_amdgcn_s_barrier();
    asm volatile("s_waitcnt lgkmcnt(0)" ::: "memory");
    __builtin_amdgcn_sched_barrier(0);
    __builtin_amdgcn_s_setprio(1);
#pragma unroll
    for (int m = 0; m < 4; ++m)
#pragma unroll
      for (int n = 0; n < 2; ++n)
#pragma unroll
        for (int ks = 0; ks < 2; ++ks)
          acc[m][n] = __builtin_amdgcn_mfma_f32_16x16x32_bf16(
              aL[m][ks], bA[n][ks], acc[m][n], 0, 0, 0);
    __builtin_amdgcn_s_setprio(0);
    __builtin_amdgcn_s_barrier();

    // ---- phase 1: read B n2-3, stage B halves of tile t+1
    bf16x8 bB[2][2];
#pragma unroll
    for (int n = 0; n < 2; ++n)
#pragma unroll
      for (int ks = 0; ks < 2; ++ks) bB[n][ks] = ldB(cur, n + 2, ks);
    if (st) { stB(nxt, 0, k1); stB(nxt, 1, k1); }
    __builtin_amdgcn_s_barrier();
    asm volatile("s_waitcnt lgkmcnt(0)" ::: "memory");
    __builtin_amdgcn_sched_barrier(0);
    __builtin_amdgcn_s_setprio(1);
#pragma unroll
    for (int m = 0; m < 4; ++m)
#pragma unroll
      for (int n = 0; n < 2; ++n)
#pragma unroll
        for (int ks = 0; ks < 2; ++ks)
          acc[m][n + 2] = __builtin_amdgcn_mfma_f32_16x16x32_bf16(
              aL[m][ks], bB[n][ks], acc[m][n + 2], 0, 0, 0);
    __builtin_amdgcn_s_setprio(0);
    __builtin_amdgcn_s_barrier();

    // ---- phase 2: read A m4-7
    bf16x8 aH[4][2];
#pragma unroll
    for (int m = 0; m < 4; ++m)
#pragma unroll
      for (int ks = 0; ks < 2; ++ks) aH[m][ks] = ldA(cur, m + 4, ks);
    __builtin_amdgcn_s_barrier();
    asm volatile("s_waitcnt lgkmcnt(0)" ::: "memory");
    __builtin_amdgcn_sched_barrier(0);
    __builtin_amdgcn_s_setprio(1);
#pragma unroll
    for (int m = 0; m < 4; ++m)
#pragma unroll
      for (int n = 0; n < 2; ++n)
#pragma unroll
        for (int ks = 0; ks < 2; ++ks)
          acc[m + 4][n] = __builtin_amdgcn_mfma_f32_16x16x32_bf16(
              aH[m][ks], bA[n][ks], acc[m + 4][n], 0, 0, 0);
    __builtin_amdgcn_s_setprio(0);
    __builtin_amdgcn_s_barrier();

    // ---- phase 3: pure MFMA, then boundary drain (tile t+1 residency)
    __builtin_amdgcn_s_setprio(1);
#pragma unroll
    for (int m = 0; m < 4; ++m)
#pragma unroll
      for (int n = 0; n < 2; ++n)
#pragma unroll
        for (int ks = 0; ks < 2; ++ks)
          acc[m + 4][n + 2] = __builtin_amdgcn_mfma_f32_16x16x32_bf16(
              aH[m][ks], bB[n][ks], acc[m + 4][n + 2], 0, 0, 0);
    __builtin_amdgcn_s_setprio(0);
    __syncthreads();  // vmcnt(0)+lgkmcnt(0)+barrier: tile t+1 resident
    cur = nxt;
  }

  // C/D (16x16): col = lane&15 (B/n dim), row = lk*4 + p (A/m dim)
  const int row0 = bym * BM + wm + (lk << 2);
  const int col0 = bxn * BN + wn;

  if constexpr (EPI == 1) {
    const int seg = (bxn * BN) / 768;  // uniform per block
    unsigned short* O = (seg == 0) ? Cb : ((seg == 1) ? Ck : Cv);
#pragma unroll
    for (int n = 0; n < 4; ++n) {
      const int col = col0 + (n << 4) + l15;
      const float bv = bias[col];
      const int cl = col - seg * 768;
#pragma unroll
      for (int m = 0; m < 8; ++m)
#pragma unroll
        for (int p = 0; p < 4; ++p)
          O[(long)(row0 + (m << 4) + p) * 768 + cl] = f2b(acc[m][n][p] + bv);
    }
  } else if constexpr (EPI == 2) {
#pragma unroll
    for (int n = 0; n < 4; ++n) {
      const int col = col0 + (n << 4) + l15;
      const float bv = bias[col];
#pragma unroll
      for (int m = 0; m < 8; ++m)
#pragma unroll
        for (int p = 0; p < 4; ++p)
          Cf[(long)(row0 + (m << 4) + p) * ldc + col] = acc[m][n][p] + bv;
    }
  } else if constexpr (EPI == 3) {
    unsigned short* C = Cb + (long)bz * bsC;
#pragma unroll
    for (int m = 0; m < 8; ++m) {
      float es[4] = {0.f, 0.f, 0.f, 0.f};
#pragma unroll
      for (int n = 0; n < 4; ++n) {
        const int col = col0 + (n << 4) + l15;
#pragma unroll
        for (int p = 0; p < 4; ++p) {
          const float e = __expf(acc[m][n][p] * scale);
          es[p] += e;
          C[(long)(row0 + (m << 4) + p) * ldc + col] = f2b(e);
        }
      }
#pragma unroll
      for (int p = 0; p < 4; ++p) {
        float s = es[p];
        s += __shfl_xor(s, 1);
        s += __shfl_xor(s, 2);
        s += __shfl_xor(s, 4);
        s += __shfl_xor(s, 8);
        if (l15 == 0)
          atomicAdd(&Z[(long)bz * 1024 + row0 + (m << 4) + p], s);
      }
    }
  } else {  // EPI 4
    unsigned short* C = Cb + (long)bz * bsC;
#pragma unroll
    for (int n = 0; n < 4; ++n) {
      const int col = col0 + (n << 4) + l15;
      const float zinv = 1.f / Z[(long)bz * 1024 + col];
#pragma unroll
      for (int m = 0; m < 8; ++m)
#pragma unroll
        for (int p = 0; p < 4; ++p)
          C[(long)(row0 + (m << 4) + p) * ldc + col] =
              f2b(acc[m][n][p] * zinv);
    }
  }
}

// merged prep: cvt_x (blocks [0,24576)) + tcvt qkv_w (next 6912) +
// tcvt proj_w (next 2304)
__global__ __launch_bounds__(256) void prep(
    const float4* __restrict__ x, ushort4* __restrict__ x_bf,
    const float* __restrict__ qkv_w, unsigned short* __restrict__ Wqkv,
    const float* __restrict__ proj_w, unsigned short* __restrict__ Wp) {
  const int blk = blockIdx.x;
  if (blk < 24576) {
    const long i = (long)blk * 256 + threadIdx.x;
    float4 f = x[i];
    ushort4 o;
    o.x = f2b(f.x); o.y = f2b(f.y); o.z = f2b(f.z); o.w = f2b(f.w);
    x_bf[i] = o;
  } else if (blk < 24576 + 6912) {
    const long i = (long)(blk - 24576) * 256 + threadIdx.x;
    const int k = (int)(i % 768);
    const int j = (int)(i / 768);
    Wqkv[i] = f2b(qkv_w[(long)k * 2304 + j]);
  } else {
    const long i = (long)(blk - 24576 - 6912) * 256 + threadIdx.x;
    const int k = (int)(i % 768);
    const int j = (int)(i / 768);
    Wp[i] = f2b(proj_w[(long)k * 768 + j]);
  }
}

// per-batch V[1024][768] -> Vt[768][1024], bf16, 64x64 LDS tiles
__global__ __launch_bounds__(256) void transpose_v(
    const unsigned short* __restrict__ V, unsigned short* __restrict__ Vt) {
  __shared__ unsigned short T[64][72];
  const int b = blockIdx.z;
  const int d0 = blockIdx.x << 6;
  const int m0 = blockIdx.y << 6;
  const unsigned short* Vb = V + (long)b * 786432;
  unsigned short* Vtb = Vt + (long)b * 786432;
  const int tid = threadIdx.x;
  const int r = tid >> 2;
  const int c4 = tid & 3;
#pragma unroll
  for (int h = 0; h < 2; ++h) {
    const int cc = (c4 + (h << 2)) << 3;
    *(uint4*)&T[r][cc] = *(const uint4*)&Vb[(long)(m0 + r) * 768 + d0 + cc];
  }
  __syncthreads();
#pragma unroll
  for (int h = 0; h < 2; ++h) {
    const int mm = (c4 + (h << 2)) << 3;
    alignas(16) unsigned short tmp[8];
#pragma unroll
    for (int e = 0; e < 8; ++e) tmp[e] = T[mm + e][r];
    *(uint4*)&Vtb[(long)(d0 + r) * 1024 + m0 + mm] = *(uint4*)tmp;
  }
}

extern "C" void kernel_launch(void* const* d_in, const int* in_sizes, int n_in,
                              void* d_out, int out_size, void* d_ws,
                              size_t ws_size, hipStream_t stream) {
  const float* x = (const float*)d_in[0];
  const float* qkv_w = (const float*)d_in[1];
  const float* qkv_b = (const float*)d_in[2];
  const float* proj_w = (const float*)d_in[3];
  const float* proj_b = (const float*)d_in[4];
  float* out = (float*)d_out;

  char* ws = (char*)d_ws;
  unsigned short* x_bf = (unsigned short*)ws;
  unsigned short* Wqkv = (unsigned short*)(ws + 50331648);
  unsigned short* Wp = (unsigned short*)(ws + 53870592);
  unsigned short* Qb = (unsigned short*)(ws + 55050240);
  unsigned short* Kb = (unsigned short*)(ws + 105381888);
  unsigned short* Vb = (unsigned short*)(ws + 155713536);
  unsigned short* Sb = (unsigned short*)(ws + 206045184);
  unsigned short* Vt = x_bf;  // x_bf dead after QKV gemm
  unsigned short* Hb = Qb;    // Q dead after scores gemm
  float* Zs = (float*)Vb;     // V dead after transpose_v

  // 1) convert inputs to bf16 (weights transposed), single dispatch
  prep<<<33792, 256, 0, stream>>>((const float4*)x, (ushort4*)x_bf, qkv_w,
                                  Wqkv, proj_w, Wp);

  // 2) QKV GEMM: [32768x768] x [2304x768]^T + bias -> Q,K,V bf16
  //    (SWAP=1: blockIdx.x = M-tile -> XCD row locality, shared W col-tile)
  gemm_nt8<1, 1><<<dim3(128, 9, 1), 512, 0, stream>>>(
      x_bf, Wqkv, Qb, Kb, Vb, nullptr, qkv_b, nullptr, 768, 768, 768, 0, 0, 0,
      0, 1.f);

  // 3) V -> V^T per batch
  transpose_v<<<dim3(12, 16, 32), 256, 0, stream>>>(Vb, Vt);

  // 3b) zero the softmax row-sum accumulator (V region is now dead)
  hipMemsetAsync(Zs, 0, 32 * 1024 * sizeof(float), stream);

  // 4) E[b] = exp(Q[b] K[b]^T / sqrt(768)) bf16 + row sums into Zs
  gemm_nt8<3, 0><<<dim3(4, 4, 32), 512, 0, stream>>>(
      Qb, Kb, Sb, nullptr, nullptr, nullptr, nullptr, Zs, 768, 768, 768, 1024,
      786432, 786432, 1048576, 0.03608439182435161f);

  // 5) O^T: hbuf[b][d][n] = (sum_m Vt[b][d][m] E[b][n][m]) / Z[b][n]
  gemm_nt8<4, 0><<<dim3(4, 3, 32), 512, 0, stream>>>(
      Vt, Sb, Hb, nullptr, nullptr, nullptr, nullptr, Zs, 1024, 1024, 1024,
      1024, 786432, 1048576, 786432, 1.f);

  // 6) proj: out[32768x768] = hbuf x Wp^T + bias, fp32
  gemm_nt8<2, 1><<<dim3(128, 3, 1), 512, 0, stream>>>(
      Hb, Wp, nullptr, nullptr, nullptr, out, proj_b, nullptr, 768, 768, 768,
      768, 0, 0, 0, 1.f);
}

// Round 3
// 553.788 us; speedup vs baseline: 1.0627x; 1.0627x over previous
//
#include <hip/hip_runtime.h>
#include <hip/hip_bf16.h>

// ---------------------------------------------------------------------------
// BlipAttention: x(32,1024,768) -> qkv -> attention -> scramble -> proj
// R7: 256x256 deep-pipelined GEMM (8 waves, BK=64, 4 sub-phases/K-tile),
//     chunk-XOR swizzle (bank conflicts measured 0), setprio around MFMA.
//     NEUTRAL vs R6: boundary __syncthreads drained vmcnt(0) every K-tile
//     (m218 "drain0" case) -> MfmaUtil stuck at 25%.
// R8: T4 counted vmcnt. Prefetch 2 tiles deep: tile t+2 staged into buf[cur]
//     during phases 2/3 of tile t (B region free after ph1 barrier, A after
//     ph2 barrier). Boundary = s_waitcnt vmcnt(8) (t+1 resident, t+2 still
//     in flight) + s_barrier — main loop never drains. Epilogue stores
//     reordered n-innermost (128B contiguous per row).
// R9: identical to R8 (R8 never ran — GPU acquisition timeout; race audit
//     re-done: WAR on Bs/As protected by phase-closing barriers, RAW on
//     tile t+2 by next-iter vmcnt(8)+barrier, tail drains at t=NT-2).
// ---------------------------------------------------------------------------

#define BM 256
#define BN 256
#define BKK 64

typedef __attribute__((ext_vector_type(8))) short bf16x8;
typedef __attribute__((ext_vector_type(4))) float f32x4;

__device__ __forceinline__ unsigned short f2b(float f) {
  unsigned int u = __float_as_uint(f);
  u = u + 0x7fffu + ((u >> 16) & 1u);
  return (unsigned short)(u >> 16);
}

__device__ __forceinline__ void g2l16(const void* g, void* l) {
  __builtin_amdgcn_global_load_lds(
      (const __attribute__((address_space(1))) unsigned int*)g,
      (__attribute__((address_space(3))) unsigned int*)l, 16, 0, 0);
}

// NT GEMM: C[m][n] = sum_k A[m][k] * B[n][k]; A,B bf16 row-major (K contig).
// EPI 1: QKV split: bias add, write Q/K/V bf16 (seg = col0/768)
// EPI 2: fp32 out + bias
// EPI 3: E = exp(v*scale) bf16 out + atomic row-sum accumulation into Z
// EPI 4: bf16 out = v * (1/Z[col])
template <int EPI, int SWAP>
__global__ __launch_bounds__(512, 2) void gemm_nt8(
    const unsigned short* __restrict__ A, const unsigned short* __restrict__ B,
    unsigned short* __restrict__ Cb, unsigned short* __restrict__ Ck,
    unsigned short* __restrict__ Cv, float* __restrict__ Cf,
    const float* __restrict__ bias, float* __restrict__ Z, int K, int lda,
    int ldb, int ldc, long bsA, long bsB, long bsC, float scale) {
  __shared__ unsigned short As[2][BM][BKK];  // 64 KB
  __shared__ unsigned short Bs[2][BN][BKK];  // 64 KB

  const int bxn = SWAP ? blockIdx.y : blockIdx.x;  // N-tile
  const int bym = SWAP ? blockIdx.x : blockIdx.y;  // M-tile
  const int bz = blockIdx.z;
  const unsigned short* Ag = A + (long)bz * bsA + (long)(bym * BM) * lda;
  const unsigned short* Bg = B + (long)bz * bsB + (long)(bxn * BN) * ldb;

  const int tid = threadIdx.x;
  const int wave = tid >> 6;
  const int lane = tid & 63;
  const int l15 = lane & 15;
  const int lk = lane >> 4;           // 0..3
  const int wm = (wave >> 2) << 7;    // wave A-row offset (0/128)
  const int wn = (wave & 3) << 6;     // wave B-row offset (0/64/128/192)

  // staging map: issue covers 8 rows x 8 chunks; lane -> row sr, chunk sc^sr
  const int sr = lane >> 3;
  const int sc = (lane & 7) ^ sr;  // pre-swizzled global 16B chunk

  f32x4 acc[8][4];
#pragma unroll
  for (int m = 0; m < 8; ++m)
#pragma unroll
    for (int n = 0; n < 4; ++n)
#pragma unroll
      for (int p = 0; p < 4; ++p) acc[m][n][p] = 0.f;

  auto stA = [&](int d, int h, int k0) {
#pragma unroll
    for (int i = 0; i < 2; ++i) {
      const int rb = (h << 7) + (wave << 4) + (i << 3);
      g2l16(Ag + (long)(rb + sr) * lda + k0 + (sc << 3), &As[d][rb][0]);
    }
  };
  auto stB = [&](int d, int h, int k0) {
#pragma unroll
    for (int i = 0; i < 2; ++i) {
      const int rb = (h << 7) + (wave << 4) + (i << 3);
      g2l16(Bg + (long)(rb + sr) * ldb + k0 + (sc << 3), &Bs[d][rb][0]);
    }
  };
  // frag reads: row r, want k-chunk c=(ks*4+lk) -> stored chunk c^(r&7)
  auto ldA = [&](int d, int m, int ks) {
    return *(const bf16x8*)&As[d][wm + (m << 4) + l15]
                              [((((ks << 2) | lk) ^ (l15 & 7)) << 3)];
  };
  auto ldB = [&](int d, int n, int ks) {
    return *(const bf16x8*)&Bs[d][wn + (n << 4) + l15]
                              [((((ks << 2) | lk) ^ (l15 & 7)) << 3)];
  };

  const int NT = K / BKK;  // always >= 2 here (12 or 16)
  // prologue: stage tile0 -> buf0, tile1 -> buf1; counted wait for tile0 only
  stA(0, 0, 0); stA(0, 1, 0); stB(0, 0, 0); stB(0, 1, 0);
  stA(1, 0, BKK); stA(1, 1, BKK); stB(1, 0, BKK); stB(1, 1, BKK);
  asm volatile("s_waitcnt vmcnt(8)" ::: "memory");
  __builtin_amdgcn_sched_barrier(0);
  __builtin_amdgcn_s_barrier();

  int cur = 0;
  for (int t = 0; t < NT; ++t) {
    const int nxt = cur ^ 1;
    const bool st2 = (t + 2 < NT);  // stage tile t+2 into buf[cur]
    const int k2 = (t + 2) * BKK;

    // ---- phase 0: read A m0-3 + B n0-1 from buf[cur]
    bf16x8 aL[4][2], bA[2][2];
#pragma unroll
    for (int m = 0; m < 4; ++m)
#pragma unroll
      for (int ks = 0; ks < 2; ++ks) aL[m][ks] = ldA(cur, m, ks);
#pragma unroll
    for (int n = 0; n < 2; ++n)
#pragma unroll
      for (int ks = 0; ks < 2; ++ks) bA[n][ks] = ldB(cur, n, ks);
    __builtin_amdgcn_s_barrier();
    asm volatile("s_waitcnt lgkmcnt(0)" ::: "memory");
    __builtin_amdgcn_sched_barrier(0);
    __builtin_amdgcn_s_setprio(1);
#pragma unroll
    for (int m = 0; m < 4; ++m)
#pragma unroll
      for (int n = 0; n < 2; ++n)
#pragma unroll
        for (int ks = 0; ks < 2; ++ks)
          acc[m][n] = __builtin_amdgcn_mfma_f32_16x16x32_bf16(
              aL[m][ks], bA[n][ks], acc[m][n], 0, 0, 0);
    __builtin_amdgcn_s_setprio(0);
    __builtin_amdgcn_s_barrier();

    // ---- phase 1: read B n2-3 (last B reads of buf[cur])
    bf16x8 bB[2][2];
#pragma unroll
    for (int n = 0; n < 2; ++n)
#pragma unroll
      for (int ks = 0; ks < 2; ++ks) bB[n][ks] = ldB(cur, n + 2, ks);
    __builtin_amdgcn_s_barrier();
    asm volatile("s_waitcnt lgkmcnt(0)" ::: "memory");
    __builtin_amdgcn_sched_barrier(0);
    __builtin_amdgcn_s_setprio(1);
#pragma unroll
    for (int m = 0; m < 4; ++m)
#pragma unroll
      for (int n = 0; n < 2; ++n)
#pragma unroll
        for (int ks = 0; ks < 2; ++ks)
          acc[m][n + 2] = __builtin_amdgcn_mfma_f32_16x16x32_bf16(
              aL[m][ks], bB[n][ks], acc[m][n + 2], 0, 0, 0);
    __builtin_amdgcn_s_setprio(0);
    __builtin_amdgcn_s_barrier();
    // all B reads of buf[cur] complete chip-wide -> Bs[cur] reusable

    // ---- phase 2: read A m4-7 (last A reads); stage t+2 B into Bs[cur]
    bf16x8 aH[4][2];
#pragma unroll
    for (int m = 0; m < 4; ++m)
#pragma unroll
      for (int ks = 0; ks < 2; ++ks) aH[m][ks] = ldA(cur, m + 4, ks);
    if (st2) { stB(cur, 0, k2); stB(cur, 1, k2); }
    __builtin_amdgcn_s_barrier();
    asm volatile("s_waitcnt lgkmcnt(0)" ::: "memory");
    __builtin_amdgcn_sched_barrier(0);
    __builtin_amdgcn_s_setprio(1);
#pragma unroll
    for (int m = 0; m < 4; ++m)
#pragma unroll
      for (int n = 0; n < 2; ++n)
#pragma unroll
        for (int ks = 0; ks < 2; ++ks)
          acc[m + 4][n] = __builtin_amdgcn_mfma_f32_16x16x32_bf16(
              aH[m][ks], bA[n][ks], acc[m + 4][n], 0, 0, 0);
    __builtin_amdgcn_s_setprio(0);
    __builtin_amdgcn_s_barrier();
    // all A reads of buf[cur] complete chip-wide -> As[cur] reusable

    // ---- phase 3: stage t+2 A into As[cur]; pure MFMA; counted boundary
    if (st2) { stA(cur, 0, k2); stA(cur, 1, k2); }
    __builtin_amdgcn_s_setprio(1);
#pragma unroll
    for (int m = 0; m < 4; ++m)
#pragma unroll
      for (int n = 0; n < 2; ++n)
#pragma unroll
        for (int ks = 0; ks < 2; ++ks)
          acc[m + 4][n + 2] = __builtin_amdgcn_mfma_f32_16x16x32_bf16(
              aH[m][ks], bB[n][ks], acc[m + 4][n + 2], 0, 0, 0);
    __builtin_amdgcn_s_setprio(0);
    // in flight: 8 loads (t+1) + (st2 ? 8 (t+2) : 0). Retire t+1's only.
    if (st2)
      asm volatile("s_waitcnt vmcnt(8)" ::: "memory");
    else
      asm volatile("s_waitcnt vmcnt(0)" ::: "memory");
    __builtin_amdgcn_sched_barrier(0);
    __builtin_amdgcn_s_barrier();
    cur = nxt;
  }

  // C/D (16x16): col = lane&15 (B/n dim), row = lk*4 + p (A/m dim)
  const int row0 = bym * BM + wm + (lk << 2);
  const int col0 = bxn * BN + wn;

  if constexpr (EPI == 1) {
    const int seg = (bxn * BN) / 768;  // uniform per block
    unsigned short* O = (seg == 0) ? Cb : ((seg == 1) ? Ck : Cv);
    float bv[4];
#pragma unroll
    for (int n = 0; n < 4; ++n) bv[n] = bias[col0 + (n << 4) + l15];
    const int cl0 = col0 + l15 - seg * 768;
#pragma unroll
    for (int m = 0; m < 8; ++m)
#pragma unroll
      for (int p = 0; p < 4; ++p) {
        const long rr = row0 + (m << 4) + p;
#pragma unroll
        for (int n = 0; n < 4; ++n)
          O[rr * 768 + cl0 + (n << 4)] = f2b(acc[m][n][p] + bv[n]);
      }
  } else if constexpr (EPI == 2) {
    float bv[4];
#pragma unroll
    for (int n = 0; n < 4; ++n) bv[n] = bias[col0 + (n << 4) + l15];
#pragma unroll
    for (int m = 0; m < 8; ++m)
#pragma unroll
      for (int p = 0; p < 4; ++p) {
        const long rr = row0 + (m << 4) + p;
#pragma unroll
        for (int n = 0; n < 4; ++n)
          Cf[rr * ldc + col0 + (n << 4) + l15] = acc[m][n][p] + bv[n];
      }
  } else if constexpr (EPI == 3) {
    unsigned short* C = Cb + (long)bz * bsC;
#pragma unroll
    for (int m = 0; m < 8; ++m) {
      float es[4] = {0.f, 0.f, 0.f, 0.f};
#pragma unroll
      for (int p = 0; p < 4; ++p) {
        const long rr = row0 + (m << 4) + p;
#pragma unroll
        for (int n = 0; n < 4; ++n) {
          const float e = __expf(acc[m][n][p] * scale);
          es[p] += e;
          C[rr * ldc + col0 + (n << 4) + l15] = f2b(e);
        }
      }
#pragma unroll
      for (int p = 0; p < 4; ++p) {
        float s = es[p];
        s += __shfl_xor(s, 1);
        s += __shfl_xor(s, 2);
        s += __shfl_xor(s, 4);
        s += __shfl_xor(s, 8);
        if (l15 == 0)
          atomicAdd(&Z[(long)bz * 1024 + row0 + (m << 4) + p], s);
      }
    }
  } else {  // EPI 4
    unsigned short* C = Cb + (long)bz * bsC;
    float zv[4];
#pragma unroll
    for (int n = 0; n < 4; ++n)
      zv[n] = 1.f / Z[(long)bz * 1024 + col0 + (n << 4) + l15];
#pragma unroll
    for (int m = 0; m < 8; ++m)
#pragma unroll
      for (int p = 0; p < 4; ++p) {
        const long rr = row0 + (m << 4) + p;
#pragma unroll
        for (int n = 0; n < 4; ++n)
          C[rr * ldc + col0 + (n << 4) + l15] = f2b(acc[m][n][p] * zv[n]);
      }
  }
}

// merged prep: cvt_x (blocks [0,24576)) + tcvt qkv_w (next 6912) +
// tcvt proj_w (next 2304)
__global__ __launch_bounds__(256) void prep(
    const float4* __restrict__ x, ushort4* __restrict__ x_bf,
    const float* __restrict__ qkv_w, unsigned short* __restrict__ Wqkv,
    const float* __restrict__ proj_w, unsigned short* __restrict__ Wp) {
  const int blk = blockIdx.x;
  if (blk < 24576) {
    const long i = (long)blk * 256 + threadIdx.x;
    float4 f = x[i];
    ushort4 o;
    o.x = f2b(f.x); o.y = f2b(f.y); o.z = f2b(f.z); o.w = f2b(f.w);
    x_bf[i] = o;
  } else if (blk < 24576 + 6912) {
    const long i = (long)(blk - 24576) * 256 + threadIdx.x;
    const int k = (int)(i % 768);
    const int j = (int)(i / 768);
    Wqkv[i] = f2b(qkv_w[(long)k * 2304 + j]);
  } else {
    const long i = (long)(blk - 24576 - 6912) * 256 + threadIdx.x;
    const int k = (int)(i % 768);
    const int j = (int)(i / 768);
    Wp[i] = f2b(proj_w[(long)k * 768 + j]);
  }
}

// per-batch V[1024][768] -> Vt[768][1024], bf16, 64x64 LDS tiles
__global__ __launch_bounds__(256) void transpose_v(
    const unsigned short* __restrict__ V, unsigned short* __restrict__ Vt) {
  __shared__ unsigned short T[64][72];
  const int b = blockIdx.z;
  const int d0 = blockIdx.x << 6;
  const int m0 = blockIdx.y << 6;
  const unsigned short* Vb = V + (long)b * 786432;
  unsigned short* Vtb = Vt + (long)b * 786432;
  const int tid = threadIdx.x;
  const int r = tid >> 2;
  const int c4 = tid & 3;
#pragma unroll
  for (int h = 0; h < 2; ++h) {
    const int cc = (c4 + (h << 2)) << 3;
    *(uint4*)&T[r][cc] = *(const uint4*)&Vb[(long)(m0 + r) * 768 + d0 + cc];
  }
  __syncthreads();
#pragma unroll
  for (int h = 0; h < 2; ++h) {
    const int mm = (c4 + (h << 2)) << 3;
    alignas(16) unsigned short tmp[8];
#pragma unroll
    for (int e = 0; e < 8; ++e) tmp[e] = T[mm + e][r];
    *(uint4*)&Vtb[(long)(d0 + r) * 1024 + m0 + mm] = *(uint4*)tmp;
  }
}

extern "C" void kernel_launch(void* const* d_in, const int* in_sizes, int n_in,
                              void* d_out, int out_size, void* d_ws,
                              size_t ws_size, hipStream_t stream) {
  const float* x = (const float*)d_in[0];
  const float* qkv_w = (const float*)d_in[1];
  const float* qkv_b = (const float*)d_in[2];
  const float* proj_w = (const float*)d_in[3];
  const float* proj_b = (const float*)d_in[4];
  float* out = (float*)d_out;

  char* ws = (char*)d_ws;
  unsigned short* x_bf = (unsigned short*)ws;
  unsigned short* Wqkv = (unsigned short*)(ws + 50331648);
  unsigned short* Wp = (unsigned short*)(ws + 53870592);
  unsigned short* Qb = (unsigned short*)(ws + 55050240);
  unsigned short* Kb = (unsigned short*)(ws + 105381888);
  unsigned short* Vb = (unsigned short*)(ws + 155713536);
  unsigned short* Sb = (unsigned short*)(ws + 206045184);
  unsigned short* Vt = x_bf;  // x_bf dead after QKV gemm
  unsigned short* Hb = Qb;    // Q dead after scores gemm
  float* Zs = (float*)Vb;     // V dead after transpose_v

  // 1) convert inputs to bf16 (weights transposed), single dispatch
  prep<<<33792, 256, 0, stream>>>((const float4*)x, (ushort4*)x_bf, qkv_w,
                                  Wqkv, proj_w, Wp);

  // 2) QKV GEMM: [32768x768] x [2304x768]^T + bias -> Q,K,V bf16
  //    (SWAP=1: blockIdx.x = M-tile -> XCD row locality, shared W col-tile)
  gemm_nt8<1, 1><<<dim3(128, 9, 1), 512, 0, stream>>>(
      x_bf, Wqkv, Qb, Kb, Vb, nullptr, qkv_b, nullptr, 768, 768, 768, 0, 0, 0,
      0, 1.f);

  // 3) V -> V^T per batch
  transpose_v<<<dim3(12, 16, 32), 256, 0, stream>>>(Vb, Vt);

  // 3b) zero the softmax row-sum accumulator (V region is now dead)
  hipMemsetAsync(Zs, 0, 32 * 1024 * sizeof(float), stream);

  // 4) E[b] = exp(Q[b] K[b]^T / sqrt(768)) bf16 + row sums into Zs
  gemm_nt8<3, 0><<<dim3(4, 4, 32), 512, 0, stream>>>(
      Qb, Kb, Sb, nullptr, nullptr, nullptr, nullptr, Zs, 768, 768, 768, 1024,
      786432, 786432, 1048576, 0.03608439182435161f);

  // 5) O^T: hbuf[b][d][n] = (sum_m Vt[b][d][m] E[b][n][m]) / Z[b][n]
  gemm_nt8<4, 0><<<dim3(4, 3, 32), 512, 0, stream>>>(
      Vt, Sb, Hb, nullptr, nullptr, nullptr, nullptr, Zs, 1024, 1024, 1024,
      1024, 786432, 1048576, 786432, 1.f);

  // 6) proj: out[32768x768] = hbuf x Wp^T + bias, fp32
  gemm_nt8<2, 1><<<dim3(128, 3, 1), 512, 0, stream>>>(
      Hb, Wp, nullptr, nullptr, nullptr, out, proj_b, nullptr, 768, 768, 768,
      768, 0, 0, 0, 1.f);
}

// Round 4
// 549.502 us; speedup vs baseline: 1.0710x; 1.0078x over previous
//
#include <hip/hip_runtime.h>
#include <hip/hip_bf16.h>

// ---------------------------------------------------------------------------
// BlipAttention: x(32,1024,768) -> qkv -> attention -> scramble -> proj
// R7: 256x256 deep-pipelined GEMM (8 waves, BK=64, 4 sub-phases/K-tile),
//     chunk-XOR swizzle (bank conflicts 0), setprio. NEUTRAL: drain0.
// R9: counted vmcnt, 2-deep prefetch, n-innermost epilogue. 588->554us,
//     QKV 185->152us, MfmaUtil 25.5->31.4, WRITE 258->147MB (=ideal).
// R10: XCD-chunked work decode (T1). FETCH was 137MB vs 54 ideal: A-panel's
//     9 N-siblings were dispatch-scattered -> staging served from L3
//     (~2100cyc/K-tile/CU) not L2. Bijective remap w=(id&7)*(total/8)+id/8,
//     decode bz / m / n-fastest: each XCD owns contiguous M-range (QKV:
//     16 A-panels; window ~1.4MB A + 3.5MB B = L2-resident) or whole
//     batches (scores/PV). Pipeline logic unchanged from R9.
// ---------------------------------------------------------------------------

#define BM 256
#define BN 256
#define BKK 64

typedef __attribute__((ext_vector_type(8))) short bf16x8;
typedef __attribute__((ext_vector_type(4))) float f32x4;

__device__ __forceinline__ unsigned short f2b(float f) {
  unsigned int u = __float_as_uint(f);
  u = u + 0x7fffu + ((u >> 16) & 1u);
  return (unsigned short)(u >> 16);
}

__device__ __forceinline__ void g2l16(const void* g, void* l) {
  __builtin_amdgcn_global_load_lds(
      (const __attribute__((address_space(1))) unsigned int*)g,
      (__attribute__((address_space(3))) unsigned int*)l, 16, 0, 0);
}

// NT GEMM: C[m][n] = sum_k A[m][k] * B[n][k]; A,B bf16 row-major (K contig).
// Work decode: flat grid, XCD-chunked (see header). MT = M-tiles, NN = N-tiles
// per batch; batches = gridDim.x / (MT*NN).
// EPI 1: QKV split: bias add, write Q/K/V bf16 (seg = col0/768)
// EPI 2: fp32 out + bias
// EPI 3: E = exp(v*scale) bf16 out + atomic row-sum accumulation into Z
// EPI 4: bf16 out = v * (1/Z[col])
template <int EPI>
__global__ __launch_bounds__(512, 2) void gemm_nt8(
    const unsigned short* __restrict__ A, const unsigned short* __restrict__ B,
    unsigned short* __restrict__ Cb, unsigned short* __restrict__ Ck,
    unsigned short* __restrict__ Cv, float* __restrict__ Cf,
    const float* __restrict__ bias, float* __restrict__ Z, int K, int lda,
    int ldb, int ldc, long bsA, long bsB, long bsC, float scale, int MT,
    int NN) {
  __shared__ unsigned short As[2][BM][BKK];  // 64 KB
  __shared__ unsigned short Bs[2][BN][BKK];  // 64 KB

  // XCD-chunked bijective remap (gridDim.x % 8 == 0 for all our launches)
  const int id = blockIdx.x;
  const int w = (id & 7) * ((int)gridDim.x >> 3) + (id >> 3);
  const int pb = MT * NN;
  const int bz = w / pb;
  const int r = w - bz * pb;
  const int bym = r / NN;   // M-tile (middle: XCD owns contiguous M-range)
  const int bxn = r - bym * NN;  // N-tile (fastest: panel siblings adjacent)

  const unsigned short* Ag = A + (long)bz * bsA + (long)(bym * BM) * lda;
  const unsigned short* Bg = B + (long)bz * bsB + (long)(bxn * BN) * ldb;

  const int tid = threadIdx.x;
  const int wave = tid >> 6;
  const int lane = tid & 63;
  const int l15 = lane & 15;
  const int lk = lane >> 4;           // 0..3
  const int wm = (wave >> 2) << 7;    // wave A-row offset (0/128)
  const int wn = (wave & 3) << 6;     // wave B-row offset (0/64/128/192)

  // staging map: issue covers 8 rows x 8 chunks; lane -> row sr, chunk sc^sr
  const int sr = lane >> 3;
  const int sc = (lane & 7) ^ sr;  // pre-swizzled global 16B chunk

  f32x4 acc[8][4];
#pragma unroll
  for (int m = 0; m < 8; ++m)
#pragma unroll
    for (int n = 0; n < 4; ++n)
#pragma unroll
      for (int p = 0; p < 4; ++p) acc[m][n][p] = 0.f;

  auto stA = [&](int d, int h, int k0) {
#pragma unroll
    for (int i = 0; i < 2; ++i) {
      const int rb = (h << 7) + (wave << 4) + (i << 3);
      g2l16(Ag + (long)(rb + sr) * lda + k0 + (sc << 3), &As[d][rb][0]);
    }
  };
  auto stB = [&](int d, int h, int k0) {
#pragma unroll
    for (int i = 0; i < 2; ++i) {
      const int rb = (h << 7) + (wave << 4) + (i << 3);
      g2l16(Bg + (long)(rb + sr) * ldb + k0 + (sc << 3), &Bs[d][rb][0]);
    }
  };
  // frag reads: row r, want k-chunk c=(ks*4+lk) -> stored chunk c^(r&7)
  auto ldA = [&](int d, int m, int ks) {
    return *(const bf16x8*)&As[d][wm + (m << 4) + l15]
                              [((((ks << 2) | lk) ^ (l15 & 7)) << 3)];
  };
  auto ldB = [&](int d, int n, int ks) {
    return *(const bf16x8*)&Bs[d][wn + (n << 4) + l15]
                              [((((ks << 2) | lk) ^ (l15 & 7)) << 3)];
  };

  const int NT = K / BKK;  // always >= 2 here (12 or 16)
  // prologue: stage tile0 -> buf0, tile1 -> buf1; counted wait for tile0 only
  stA(0, 0, 0); stA(0, 1, 0); stB(0, 0, 0); stB(0, 1, 0);
  stA(1, 0, BKK); stA(1, 1, BKK); stB(1, 0, BKK); stB(1, 1, BKK);
  asm volatile("s_waitcnt vmcnt(8)" ::: "memory");
  __builtin_amdgcn_sched_barrier(0);
  __builtin_amdgcn_s_barrier();

  int cur = 0;
  for (int t = 0; t < NT; ++t) {
    const int nxt = cur ^ 1;
    const bool st2 = (t + 2 < NT);  // stage tile t+2 into buf[cur]
    const int k2 = (t + 2) * BKK;

    // ---- phase 0: read A m0-3 + B n0-1 from buf[cur]
    bf16x8 aL[4][2], bA[2][2];
#pragma unroll
    for (int m = 0; m < 4; ++m)
#pragma unroll
      for (int ks = 0; ks < 2; ++ks) aL[m][ks] = ldA(cur, m, ks);
#pragma unroll
    for (int n = 0; n < 2; ++n)
#pragma unroll
      for (int ks = 0; ks < 2; ++ks) bA[n][ks] = ldB(cur, n, ks);
    __builtin_amdgcn_s_barrier();
    asm volatile("s_waitcnt lgkmcnt(0)" ::: "memory");
    __builtin_amdgcn_sched_barrier(0);
    __builtin_amdgcn_s_setprio(1);
#pragma unroll
    for (int m = 0; m < 4; ++m)
#pragma unroll
      for (int n = 0; n < 2; ++n)
#pragma unroll
        for (int ks = 0; ks < 2; ++ks)
          acc[m][n] = __builtin_amdgcn_mfma_f32_16x16x32_bf16(
              aL[m][ks], bA[n][ks], acc[m][n], 0, 0, 0);
    __builtin_amdgcn_s_setprio(0);
    __builtin_amdgcn_s_barrier();

    // ---- phase 1: read B n2-3 (last B reads of buf[cur])
    bf16x8 bB[2][2];
#pragma unroll
    for (int n = 0; n < 2; ++n)
#pragma unroll
      for (int ks = 0; ks < 2; ++ks) bB[n][ks] = ldB(cur, n + 2, ks);
    __builtin_amdgcn_s_barrier();
    asm volatile("s_waitcnt lgkmcnt(0)" ::: "memory");
    __builtin_amdgcn_sched_barrier(0);
    __builtin_amdgcn_s_setprio(1);
#pragma unroll
    for (int m = 0; m < 4; ++m)
#pragma unroll
      for (int n = 0; n < 2; ++n)
#pragma unroll
        for (int ks = 0; ks < 2; ++ks)
          acc[m][n + 2] = __builtin_amdgcn_mfma_f32_16x16x32_bf16(
              aL[m][ks], bB[n][ks], acc[m][n + 2], 0, 0, 0);
    __builtin_amdgcn_s_setprio(0);
    __builtin_amdgcn_s_barrier();
    // all B reads of buf[cur] complete chip-wide -> Bs[cur] reusable

    // ---- phase 2: read A m4-7 (last A reads); stage t+2 B into Bs[cur]
    bf16x8 aH[4][2];
#pragma unroll
    for (int m = 0; m < 4; ++m)
#pragma unroll
      for (int ks = 0; ks < 2; ++ks) aH[m][ks] = ldA(cur, m + 4, ks);
    if (st2) { stB(cur, 0, k2); stB(cur, 1, k2); }
    __builtin_amdgcn_s_barrier();
    asm volatile("s_waitcnt lgkmcnt(0)" ::: "memory");
    __builtin_amdgcn_sched_barrier(0);
    __builtin_amdgcn_s_setprio(1);
#pragma unroll
    for (int m = 0; m < 4; ++m)
#pragma unroll
      for (int n = 0; n < 2; ++n)
#pragma unroll
        for (int ks = 0; ks < 2; ++ks)
          acc[m + 4][n] = __builtin_amdgcn_mfma_f32_16x16x32_bf16(
              aH[m][ks], bA[n][ks], acc[m + 4][n], 0, 0, 0);
    __builtin_amdgcn_s_setprio(0);
    __builtin_amdgcn_s_barrier();
    // all A reads of buf[cur] complete chip-wide -> As[cur] reusable

    // ---- phase 3: stage t+2 A into As[cur]; pure MFMA; counted boundary
    if (st2) { stA(cur, 0, k2); stA(cur, 1, k2); }
    __builtin_amdgcn_s_setprio(1);
#pragma unroll
    for (int m = 0; m < 4; ++m)
#pragma unroll
      for (int n = 0; n < 2; ++n)
#pragma unroll
        for (int ks = 0; ks < 2; ++ks)
          acc[m + 4][n + 2] = __builtin_amdgcn_mfma_f32_16x16x32_bf16(
              aH[m][ks], bB[n][ks], acc[m + 4][n + 2], 0, 0, 0);
    __builtin_amdgcn_s_setprio(0);
    // in flight: 8 loads (t+1) + (st2 ? 8 (t+2) : 0). Retire t+1's only.
    if (st2)
      asm volatile("s_waitcnt vmcnt(8)" ::: "memory");
    else
      asm volatile("s_waitcnt vmcnt(0)" ::: "memory");
    __builtin_amdgcn_sched_barrier(0);
    __builtin_amdgcn_s_barrier();
    cur = nxt;
  }

  // C/D (16x16): col = lane&15 (B/n dim), row = lk*4 + p (A/m dim)
  const int row0 = bym * BM + wm + (lk << 2);
  const int col0 = bxn * BN + wn;

  if constexpr (EPI == 1) {
    const int seg = (bxn * BN) / 768;  // uniform per block (768 % 256 == 0)
    unsigned short* O = (seg == 0) ? Cb : ((seg == 1) ? Ck : Cv);
    float bv[4];
#pragma unroll
    for (int n = 0; n < 4; ++n) bv[n] = bias[col0 + (n << 4) + l15];
    const int cl0 = col0 + l15 - seg * 768;
#pragma unroll
    for (int m = 0; m < 8; ++m)
#pragma unroll
      for (int p = 0; p < 4; ++p) {
        const long rr = row0 + (m << 4) + p;
#pragma unroll
        for (int n = 0; n < 4; ++n)
          O[rr * 768 + cl0 + (n << 4)] = f2b(acc[m][n][p] + bv[n]);
      }
  } else if constexpr (EPI == 2) {
    float bv[4];
#pragma unroll
    for (int n = 0; n < 4; ++n) bv[n] = bias[col0 + (n << 4) + l15];
#pragma unroll
    for (int m = 0; m < 8; ++m)
#pragma unroll
      for (int p = 0; p < 4; ++p) {
        const long rr = row0 + (m << 4) + p;
#pragma unroll
        for (int n = 0; n < 4; ++n)
          Cf[rr * ldc + col0 + (n << 4) + l15] = acc[m][n][p] + bv[n];
      }
  } else if constexpr (EPI == 3) {
    unsigned short* C = Cb + (long)bz * bsC;
#pragma unroll
    for (int m = 0; m < 8; ++m) {
      float es[4] = {0.f, 0.f, 0.f, 0.f};
#pragma unroll
      for (int p = 0; p < 4; ++p) {
        const long rr = row0 + (m << 4) + p;
#pragma unroll
        for (int n = 0; n < 4; ++n) {
          const float e = __expf(acc[m][n][p] * scale);
          es[p] += e;
          C[rr * ldc + col0 + (n << 4) + l15] = f2b(e);
        }
      }
#pragma unroll
      for (int p = 0; p < 4; ++p) {
        float s = es[p];
        s += __shfl_xor(s, 1);
        s += __shfl_xor(s, 2);
        s += __shfl_xor(s, 4);
        s += __shfl_xor(s, 8);
        if (l15 == 0)
          atomicAdd(&Z[(long)bz * 1024 + row0 + (m << 4) + p], s);
      }
    }
  } else {  // EPI 4
    unsigned short* C = Cb + (long)bz * bsC;
    float zv[4];
#pragma unroll
    for (int n = 0; n < 4; ++n)
      zv[n] = 1.f / Z[(long)bz * 1024 + col0 + (n << 4) + l15];
#pragma unroll
    for (int m = 0; m < 8; ++m)
#pragma unroll
      for (int p = 0; p < 4; ++p) {
        const long rr = row0 + (m << 4) + p;
#pragma unroll
        for (int n = 0; n < 4; ++n)
          C[rr * ldc + col0 + (n << 4) + l15] = f2b(acc[m][n][p] * zv[n]);
      }
  }
}

// merged prep: cvt_x (blocks [0,24576)) + tcvt qkv_w (next 6912) +
// tcvt proj_w (next 2304)
__global__ __launch_bounds__(256) void prep(
    const float4* __restrict__ x, ushort4* __restrict__ x_bf,
    const float* __restrict__ qkv_w, unsigned short* __restrict__ Wqkv,
    const float* __restrict__ proj_w, unsigned short* __restrict__ Wp) {
  const int blk = blockIdx.x;
  if (blk < 24576) {
    const long i = (long)blk * 256 + threadIdx.x;
    float4 f = x[i];
    ushort4 o;
    o.x = f2b(f.x); o.y = f2b(f.y); o.z = f2b(f.z); o.w = f2b(f.w);
    x_bf[i] = o;
  } else if (blk < 24576 + 6912) {
    const long i = (long)(blk - 24576) * 256 + threadIdx.x;
    const int k = (int)(i % 768);
    const int j = (int)(i / 768);
    Wqkv[i] = f2b(qkv_w[(long)k * 2304 + j]);
  } else {
    const long i = (long)(blk - 24576 - 6912) * 256 + threadIdx.x;
    const int k = (int)(i % 768);
    const int j = (int)(i / 768);
    Wp[i] = f2b(proj_w[(long)k * 768 + j]);
  }
}

// per-batch V[1024][768] -> Vt[768][1024], bf16, 64x64 LDS tiles
__global__ __launch_bounds__(256) void transpose_v(
    const unsigned short* __restrict__ V, unsigned short* __restrict__ Vt) {
  __shared__ unsigned short T[64][72];
  const int b = blockIdx.z;
  const int d0 = blockIdx.x << 6;
  const int m0 = blockIdx.y << 6;
  const unsigned short* Vb = V + (long)b * 786432;
  unsigned short* Vtb = Vt + (long)b * 786432;
  const int tid = threadIdx.x;
  const int r = tid >> 2;
  const int c4 = tid & 3;
#pragma unroll
  for (int h = 0; h < 2; ++h) {
    const int cc = (c4 + (h << 2)) << 3;
    *(uint4*)&T[r][cc] = *(const uint4*)&Vb[(long)(m0 + r) * 768 + d0 + cc];
  }
  __syncthreads();
#pragma unroll
  for (int h = 0; h < 2; ++h) {
    const int mm = (c4 + (h << 2)) << 3;
    alignas(16) unsigned short tmp[8];
#pragma unroll
    for (int e = 0; e < 8; ++e) tmp[e] = T[mm + e][r];
    *(uint4*)&Vtb[(long)(d0 + r) * 1024 + m0 + mm] = *(uint4*)tmp;
  }
}

extern "C" void kernel_launch(void* const* d_in, const int* in_sizes, int n_in,
                              void* d_out, int out_size, void* d_ws,
                              size_t ws_size, hipStream_t stream) {
  const float* x = (const float*)d_in[0];
  const float* qkv_w = (const float*)d_in[1];
  const float* qkv_b = (const float*)d_in[2];
  const float* proj_w = (const float*)d_in[3];
  const float* proj_b = (const float*)d_in[4];
  float* out = (float*)d_out;

  char* ws = (char*)d_ws;
  unsigned short* x_bf = (unsigned short*)ws;
  unsigned short* Wqkv = (unsigned short*)(ws + 50331648);
  unsigned short* Wp = (unsigned short*)(ws + 53870592);
  unsigned short* Qb = (unsigned short*)(ws + 55050240);
  unsigned short* Kb = (unsigned short*)(ws + 105381888);
  unsigned short* Vb = (unsigned short*)(ws + 155713536);
  unsigned short* Sb = (unsigned short*)(ws + 206045184);
  unsigned short* Vt = x_bf;  // x_bf dead after QKV gemm
  unsigned short* Hb = Qb;    // Q dead after scores gemm
  float* Zs = (float*)Vb;     // V dead after transpose_v

  // 1) convert inputs to bf16 (weights transposed), single dispatch
  prep<<<33792, 256, 0, stream>>>((const float4*)x, (ushort4*)x_bf, qkv_w,
                                  Wqkv, proj_w, Wp);

  // 2) QKV GEMM: [32768x768] x [2304x768]^T + bias -> Q,K,V bf16
  //    MT=128, NN=9: each XCD owns 16 contiguous A-panels, N fastest.
  gemm_nt8<1><<<1152, 512, 0, stream>>>(
      x_bf, Wqkv, Qb, Kb, Vb, nullptr, qkv_b, nullptr, 768, 768, 768, 0, 0, 0,
      0, 1.f, 128, 9);

  // 3) V -> V^T per batch
  transpose_v<<<dim3(12, 16, 32), 256, 0, stream>>>(Vb, Vt);

  // 3b) zero the softmax row-sum accumulator (V region is now dead)
  hipMemsetAsync(Zs, 0, 32 * 1024 * sizeof(float), stream);

  // 4) E[b] = exp(Q[b] K[b]^T / sqrt(768)) bf16 + row sums into Zs
  //    MT=4, NN=4, 32 batches: each XCD owns 4 whole batches.
  gemm_nt8<3><<<512, 512, 0, stream>>>(
      Qb, Kb, Sb, nullptr, nullptr, nullptr, nullptr, Zs, 768, 768, 768, 1024,
      786432, 786432, 1048576, 0.03608439182435161f, 4, 4);

  // 5) O^T: hbuf[b][d][n] = (sum_m Vt[b][d][m] E[b][n][m]) / Z[b][n]
  //    MT=3, NN=4 per batch.
  gemm_nt8<4><<<384, 512, 0, stream>>>(
      Vt, Sb, Hb, nullptr, nullptr, nullptr, nullptr, Zs, 1024, 1024, 1024,
      1024, 786432, 1048576, 786432, 1.f, 3, 4);

  // 6) proj: out[32768x768] = hbuf x Wp^T + bias, fp32. MT=128, NN=3.
  gemm_nt8<2><<<384, 512, 0, stream>>>(
      Hb, Wp, nullptr, nullptr, nullptr, out, proj_b, nullptr, 768, 768, 768,
      768, 0, 0, 0, 1.f, 128, 3);
}